// Round 2
// baseline (778.974 us; speedup 1.0000x reference)
//
#include <hip/hip_runtime.h>
#include <hip/hip_bf16.h>

using u16 = unsigned short;
typedef short v8s __attribute__((ext_vector_type(8)));
typedef float v4f __attribute__((ext_vector_type(4)));

#define B_ 2
#define T_ 2048
#define C_ 1024
#define NH_ 16
#define HD_ 64
#define FF_ 4096
#define NT (B_*T_)

__device__ __forceinline__ float b2f(u16 u) {
  union { unsigned int i; float f; } v; v.i = ((unsigned int)u) << 16; return v.f;
}
__device__ __forceinline__ u16 f2b(float f) {
  union { float f; unsigned int i; } v; v.f = f;
  unsigned int r = (v.i + 0x7FFFu + ((v.i >> 16) & 1u)) >> 16;
  return (u16)r;
}
__device__ __forceinline__ v4f mfma16(v8s a, v8s b, v4f c) {
  return __builtin_amdgcn_mfma_f32_16x16x32_bf16(a, b, c, 0, 0, 0);
}

// ------- LayerNorm: fp32 in -> bf16 out, one block per row (C=1024) -------
__global__ __launch_bounds__(256) void ln_kernel(const float* __restrict__ x,
    const float* __restrict__ w, const float* __restrict__ b, u16* __restrict__ y) {
  int row = blockIdx.x;
  int tid = threadIdx.x;
  const float* xr = x + (size_t)row * C_;
  float4 f4 = *(const float4*)&xr[tid * 4];
  float f[4] = {f4.x, f4.y, f4.z, f4.w};
  float s1 = 0.f, s2 = 0.f;
#pragma unroll
  for (int i = 0; i < 4; ++i) { s1 += f[i]; s2 += f[i] * f[i]; }
#pragma unroll
  for (int off = 32; off > 0; off >>= 1) {
    s1 += __shfl_down(s1, off);
    s2 += __shfl_down(s2, off);
  }
  __shared__ float red[10];
  int lane = tid & 63, wid = tid >> 6;
  if (lane == 0) { red[wid] = s1; red[4 + wid] = s2; }
  __syncthreads();
  if (tid == 0) {
    float a = red[0] + red[1] + red[2] + red[3];
    float q = red[4] + red[5] + red[6] + red[7];
    float mu = a * (1.f / C_);
    float var = q * (1.f / C_) - mu * mu;
    red[8] = mu; red[9] = rsqrtf(var + 1e-5f);
  }
  __syncthreads();
  float mu = red[8], rs = red[9];
  union { uint2 v; u16 s[4]; } st;
#pragma unroll
  for (int i = 0; i < 4; ++i) {
    int c = tid * 4 + i;
    st.s[i] = f2b((f[i] - mu) * rs * w[c] + b[c]);
  }
  *(uint2*)&y[(size_t)row * C_ + tid * 4] = st.v;
}

// ------- GEMM: Y[M,N] = Xbf16[M,K] @ Wf32[K,N] (+bias)(+res)(relu) -------
// 64x64x32 tile, 256 thr = 4 waves (2x2), each wave 32x32 via 2x2 mfma frags
__global__ __launch_bounds__(256) void gemm_kernel(const u16* __restrict__ X,
    const float* __restrict__ W, const float* __restrict__ bias,
    const float* __restrict__ resf, u16* __restrict__ Yb, float* __restrict__ Yf,
    int M, int N, int K, int relu) {
  __shared__ __align__(16) u16 As[64 * 40];
  __shared__ __align__(16) u16 Bs[64 * 40];
  int tid = threadIdx.x, lane = tid & 63, wid = tid >> 6;
  int wm = wid >> 1, wn = wid & 1, quad = lane >> 4, lcol = lane & 15;
  int m0 = blockIdx.y * 64, n0 = blockIdx.x * 64;
  v4f zero = {0.f, 0.f, 0.f, 0.f};
  v4f acc[2][2];
  acc[0][0] = zero; acc[0][1] = zero; acc[1][0] = zero; acc[1][1] = zero;
  int ar = tid >> 2, ag = tid & 3;   // A stage: row 0..63, k-group 0..3
  int bk = tid >> 3, bn = tid & 7;   // B stage: k-row 0..31, n-group 0..7
  for (int k0 = 0; k0 < K; k0 += 32) {
    *(uint4*)&As[ar * 40 + ag * 8] =
        *(const uint4*)&X[(size_t)(m0 + ar) * K + k0 + ag * 8];
    const float* wp = &W[(size_t)(k0 + bk) * N + n0 + bn * 8];
    float4 w0 = *(const float4*)wp;
    float4 w1 = *(const float4*)(wp + 4);
    int bb = (bn * 8) * 40 + bk;
    Bs[bb + 0 * 40] = f2b(w0.x);
    Bs[bb + 1 * 40] = f2b(w0.y);
    Bs[bb + 2 * 40] = f2b(w0.z);
    Bs[bb + 3 * 40] = f2b(w0.w);
    Bs[bb + 4 * 40] = f2b(w1.x);
    Bs[bb + 5 * 40] = f2b(w1.y);
    Bs[bb + 6 * 40] = f2b(w1.z);
    Bs[bb + 7 * 40] = f2b(w1.w);
    __syncthreads();
    v8s a0 = *(v8s*)&As[(wm * 32 + lcol) * 40 + quad * 8];
    v8s a1 = *(v8s*)&As[(wm * 32 + 16 + lcol) * 40 + quad * 8];
    v8s b0 = *(v8s*)&Bs[(wn * 32 + lcol) * 40 + quad * 8];
    v8s b1 = *(v8s*)&Bs[(wn * 32 + 16 + lcol) * 40 + quad * 8];
    acc[0][0] = mfma16(a0, b0, acc[0][0]);
    acc[0][1] = mfma16(a0, b1, acc[0][1]);
    acc[1][0] = mfma16(a1, b0, acc[1][0]);
    acc[1][1] = mfma16(a1, b1, acc[1][1]);
    __syncthreads();
  }
#pragma unroll
  for (int i = 0; i < 2; ++i)
#pragma unroll
    for (int j = 0; j < 2; ++j)
#pragma unroll
      for (int reg = 0; reg < 4; ++reg) {
        int m = m0 + wm * 32 + i * 16 + quad * 4 + reg;
        int n = n0 + wn * 32 + j * 16 + lcol;
        float v = acc[i][j][reg];
        if (bias) v += bias[n];
        if (resf) v += resf[(size_t)m * N + n];
        if (relu) v = fmaxf(v, 0.f);
        if (Yb) Yb[(size_t)m * N + n] = f2b(v);
        else    Yf[(size_t)m * N + n] = v;
      }
}

// ------- Flash attention (causal), bf16 QKV, 64-query tile per block -----
__global__ __launch_bounds__(256) void attn_kernel(const u16* __restrict__ Qb,
    const u16* __restrict__ Kb, const u16* __restrict__ Vb, u16* __restrict__ Ob) {
  int bh = blockIdx.x;  // b*NH + h
  int qt = blockIdx.y;
  int b = bh >> 4, h = bh & 15;
  int tid = threadIdx.x, lane = tid & 63, wid = tid >> 6;
  int quad = lane >> 4, lcol = lane & 15;
  __shared__ __align__(16) u16 Qs[64 * 72];
  __shared__ __align__(16) u16 Ks[64 * 72];
  __shared__ __align__(16) u16 Vts[64 * 72];
  __shared__ __align__(16) u16 Ps[4][16 * 72];
  int r = tid >> 2, g = tid & 3;
  size_t qrow = ((size_t)(b * T_ + qt * 64 + r)) * C_ + h * HD_;
  *(uint4*)&Qs[r * 72 + g * 8]      = *(const uint4*)&Qb[qrow + g * 8];
  *(uint4*)&Qs[r * 72 + 32 + g * 8] = *(const uint4*)&Qb[qrow + 32 + g * 8];
  __syncthreads();
  v8s aq0 = *(v8s*)&Qs[(wid * 16 + lcol) * 72 + quad * 8];
  v8s aq1 = *(v8s*)&Qs[(wid * 16 + lcol) * 72 + 32 + quad * 8];
  float m_i[4], l_i[4];
  v4f accO[4];
  v4f zero = {0.f, 0.f, 0.f, 0.f};
#pragma unroll
  for (int i = 0; i < 4; ++i) { m_i[i] = -__builtin_inff(); l_i[i] = 0.f; accO[i] = zero; }
  int nkb = qt + 1;
  for (int kb = 0; kb < nkb; ++kb) {
    __syncthreads();
    size_t krow = ((size_t)(b * T_ + kb * 64 + r)) * C_ + h * HD_;
    *(uint4*)&Ks[r * 72 + g * 8]      = *(const uint4*)&Kb[krow + g * 8];
    *(uint4*)&Ks[r * 72 + 32 + g * 8] = *(const uint4*)&Kb[krow + 32 + g * 8];
    union { uint4 v; u16 s[8]; } vv;
    vv.v = *(const uint4*)&Vb[krow + g * 8];
#pragma unroll
    for (int e = 0; e < 8; ++e) Vts[(g * 8 + e) * 72 + r] = vv.s[e];
    vv.v = *(const uint4*)&Vb[krow + 32 + g * 8];
#pragma unroll
    for (int e = 0; e < 8; ++e) Vts[(32 + g * 8 + e) * 72 + r] = vv.s[e];
    __syncthreads();
    // scores: 16 q-rows x 64 keys per wave
    float sc[4][4], p[4][4], mx[4];
#pragma unroll
    for (int reg = 0; reg < 4; ++reg) mx[reg] = -__builtin_inff();
#pragma unroll
    for (int cg = 0; cg < 4; ++cg) {
      v4f acc = zero;
      v8s bk0 = *(v8s*)&Ks[(cg * 16 + lcol) * 72 + quad * 8];
      v8s bk1 = *(v8s*)&Ks[(cg * 16 + lcol) * 72 + 32 + quad * 8];
      acc = mfma16(aq0, bk0, acc);
      acc = mfma16(aq1, bk1, acc);
      int tk = kb * 64 + cg * 16 + lcol;
#pragma unroll
      for (int reg = 0; reg < 4; ++reg) {
        int tq = qt * 64 + wid * 16 + quad * 4 + reg;
        float s = (tk <= tq) ? acc[reg] * 0.125f : -__builtin_inff();
        sc[cg][reg] = s;
        mx[reg] = fmaxf(mx[reg], s);
      }
    }
#pragma unroll
    for (int reg = 0; reg < 4; ++reg) {
      float v = mx[reg];
      v = fmaxf(v, __shfl_xor(v, 1));
      v = fmaxf(v, __shfl_xor(v, 2));
      v = fmaxf(v, __shfl_xor(v, 4));
      v = fmaxf(v, __shfl_xor(v, 8));
      float mnew = fmaxf(m_i[reg], v);
      float alpha = exp2f((m_i[reg] - mnew) * 1.44269504f);
      float ps = 0.f;
#pragma unroll
      for (int cg = 0; cg < 4; ++cg) {
        float pv = exp2f((sc[cg][reg] - mnew) * 1.44269504f);
        p[cg][reg] = pv;
        ps += pv;
      }
      ps += __shfl_xor(ps, 1);
      ps += __shfl_xor(ps, 2);
      ps += __shfl_xor(ps, 4);
      ps += __shfl_xor(ps, 8);
      l_i[reg] = l_i[reg] * alpha + ps;
      m_i[reg] = mnew;
#pragma unroll
      for (int df = 0; df < 4; ++df) accO[df][reg] *= alpha;
    }
    // P: C-layout -> LDS -> A-layout
#pragma unroll
    for (int cg = 0; cg < 4; ++cg)
#pragma unroll
      for (int reg = 0; reg < 4; ++reg)
        Ps[wid][(quad * 4 + reg) * 72 + cg * 16 + lcol] = f2b(p[cg][reg]);
    __syncthreads();
#pragma unroll
    for (int ks = 0; ks < 2; ++ks) {
      v8s ap = *(v8s*)&Ps[wid][lcol * 72 + ks * 32 + quad * 8];
#pragma unroll
      for (int df = 0; df < 4; ++df) {
        v8s bv = *(v8s*)&Vts[(df * 16 + lcol) * 72 + ks * 32 + quad * 8];
        accO[df] = mfma16(ap, bv, accO[df]);
      }
    }
  }
#pragma unroll
  for (int df = 0; df < 4; ++df)
#pragma unroll
    for (int reg = 0; reg < 4; ++reg) {
      int q = qt * 64 + wid * 16 + quad * 4 + reg;
      float o = accO[df][reg] / l_i[reg];
      Ob[((size_t)(b * T_ + q)) * C_ + h * HD_ + df * 16 + lcol] = f2b(o);
    }
}

extern "C" void kernel_launch(void* const* d_in, const int* in_sizes, int n_in,
                              void* d_out, int out_size, void* d_ws, size_t ws_size,
                              hipStream_t stream) {
  (void)in_sizes; (void)n_in; (void)out_size; (void)ws_size;
  const float* x    = (const float*)d_in[0];
  const float* ln1w = (const float*)d_in[1];
  const float* ln1b = (const float*)d_in[2];
  const float* Wq   = (const float*)d_in[3];
  const float* Wk   = (const float*)d_in[4];
  const float* Wv   = (const float*)d_in[5];
  const float* Wp   = (const float*)d_in[6];
  const float* bp   = (const float*)d_in[7];
  const float* ln2w = (const float*)d_in[8];
  const float* ln2b = (const float*)d_in[9];
  const float* W1   = (const float*)d_in[10];
  const float* b1   = (const float*)d_in[11];
  const float* W2   = (const float*)d_in[12];
  const float* b2   = (const float*)d_in[13];
  float* out = (float*)d_out;
  char* ws = (char*)d_ws;
  const size_t SEG = (size_t)NT * C_ * 2;  // 8 MiB per [4096,1024] bf16 buffer
  u16*   h1 = (u16*)(ws);                  // dead after QKV gemms
  u16*   Qb = (u16*)(ws + SEG);
  u16*   Kb = (u16*)(ws + 2 * SEG);
  u16*   Vb = (u16*)(ws + 3 * SEG);
  u16*   Ob = (u16*)(ws + 4 * SEG);
  float* xa = (float*)(ws + 5 * SEG);      // fp32, 16 MiB: 40M..56M
  u16*   h2 = (u16*)(ws);                  // overlays h1 (dead)
  u16*   f1 = (u16*)(ws + SEG);            // 32 MiB, overlays Qb..Ob (dead)

  ln_kernel<<<NT, 256, 0, stream>>>(x, ln1w, ln1b, h1);
  gemm_kernel<<<dim3(C_ / 64, NT / 64), 256, 0, stream>>>(h1, Wq, nullptr, nullptr, Qb, nullptr, NT, C_, C_, 0);
  gemm_kernel<<<dim3(C_ / 64, NT / 64), 256, 0, stream>>>(h1, Wk, nullptr, nullptr, Kb, nullptr, NT, C_, C_, 0);
  gemm_kernel<<<dim3(C_ / 64, NT / 64), 256, 0, stream>>>(h1, Wv, nullptr, nullptr, Vb, nullptr, NT, C_, C_, 0);
  attn_kernel<<<dim3(B_ * NH_, T_ / 64), 256, 0, stream>>>(Qb, Kb, Vb, Ob);
  gemm_kernel<<<dim3(C_ / 64, NT / 64), 256, 0, stream>>>(Ob, Wp, bp, x, nullptr, xa, NT, C_, C_, 0);
  ln_kernel<<<NT, 256, 0, stream>>>(xa, ln2w, ln2b, h2);
  gemm_kernel<<<dim3(FF_ / 64, NT / 64), 256, 0, stream>>>(h2, W1, b1, nullptr, f1, nullptr, NT, FF_, C_, 1);
  gemm_kernel<<<dim3(C_ / 64, NT / 64), 256, 0, stream>>>(f1, W2, b2, xa, nullptr, out, NT, C_, FF_, 0);
}

// Round 4
// 543.714 us; speedup vs baseline: 1.4327x; 1.4327x over previous
//
#include <hip/hip_runtime.h>
#include <hip/hip_bf16.h>

using u16 = unsigned short;
typedef short v8s __attribute__((ext_vector_type(8)));
typedef float v4f __attribute__((ext_vector_type(4)));

#define B_ 2
#define T_ 2048
#define C_ 1024
#define NH_ 16
#define HD_ 64
#define FF_ 4096
#define NT (B_*T_)
#define QKVC 3072

__device__ __forceinline__ u16 f2b(float f) {
  union { float f; unsigned int i; } v; v.f = f;
  unsigned int r = (v.i + 0x7FFFu + ((v.i >> 16) & 1u)) >> 16;
  return (u16)r;
}
__device__ __forceinline__ v4f mfma16(v8s a, v8s b, v4f c) {
  return __builtin_amdgcn_mfma_f32_16x16x32_bf16(a, b, c, 0, 0, 0);
}
__device__ __forceinline__ void glds16(const u16* g, u16* l) {
  __builtin_amdgcn_global_load_lds(
      (const __attribute__((address_space(1))) unsigned int*)g,
      (__attribute__((address_space(3))) unsigned int*)l, 16, 0, 0);
}

// ------- weight convert+transpose: W[K,N] fp32 -> Wt[N,K] bf16 -------
__global__ __launch_bounds__(256) void wcvt_kernel(const float* __restrict__ W,
    u16* __restrict__ Wt, int K, int N) {
  __shared__ float t[32][33];
  int tx = threadIdx.x & 31, ty = threadIdx.x >> 5;
  int n0 = blockIdx.x * 32, k0 = blockIdx.y * 32;
#pragma unroll
  for (int j = 0; j < 4; ++j)
    t[ty + j * 8][tx] = W[(size_t)(k0 + ty + j * 8) * N + n0 + tx];
  __syncthreads();
#pragma unroll
  for (int j = 0; j < 4; ++j)
    Wt[(size_t)(n0 + ty + j * 8) * K + k0 + tx] = f2b(t[tx][ty + j * 8]);
}

// ------- LayerNorm: fp32 in -> bf16 out, one block per row (C=1024) -------
__global__ __launch_bounds__(256) void ln_kernel(const float* __restrict__ x,
    const float* __restrict__ w, const float* __restrict__ b, u16* __restrict__ y) {
  int row = blockIdx.x;
  int tid = threadIdx.x;
  const float* xr = x + (size_t)row * C_;
  float4 f4 = *(const float4*)&xr[tid * 4];
  float f[4] = {f4.x, f4.y, f4.z, f4.w};
  float s1 = 0.f, s2 = 0.f;
#pragma unroll
  for (int i = 0; i < 4; ++i) { s1 += f[i]; s2 += f[i] * f[i]; }
#pragma unroll
  for (int off = 32; off > 0; off >>= 1) {
    s1 += __shfl_down(s1, off);
    s2 += __shfl_down(s2, off);
  }
  __shared__ float red[10];
  int lane = tid & 63, wid = tid >> 6;
  if (lane == 0) { red[wid] = s1; red[4 + wid] = s2; }
  __syncthreads();
  if (tid == 0) {
    float a = red[0] + red[1] + red[2] + red[3];
    float q = red[4] + red[5] + red[6] + red[7];
    float mu = a * (1.f / C_);
    float var = q * (1.f / C_) - mu * mu;
    red[8] = mu; red[9] = rsqrtf(var + 1e-5f);
  }
  __syncthreads();
  float mu = red[8], rs = red[9];
  union { uint2 v; u16 s[4]; } st;
#pragma unroll
  for (int i = 0; i < 4; ++i) {
    int c = tid * 4 + i;
    st.s[i] = f2b((f[i] - mu) * rs * w[c] + b[c]);
  }
  *(uint2*)&y[(size_t)row * C_ + tid * 4] = st.v;
}

// ------- GEMM (m97 structure): Y[M,N] = X[M,K] @ Wt[N,K]^T -------------
// 128x128x32 tile, 256 thr = 4 waves (2x2), each wave 64x64 via 4x4 frags.
// A,B staged with global_load_lds width=16 into unpadded [row][k] LDS.
__global__ __launch_bounds__(256) void gemm_bt(const u16* __restrict__ X,
    const u16* __restrict__ Wt, const float* __restrict__ bias,
    const float* __restrict__ resf, u16* __restrict__ Yb, float* __restrict__ Yf,
    int M, int N, int K, int relu) {
  __shared__ __align__(16) u16 As[128 * 32];
  __shared__ __align__(16) u16 Bs[128 * 32];
  int tid = threadIdx.x, lane = tid & 63, w = tid >> 6;
  int wm = w >> 1, wn = w & 1, quad = lane >> 4, lcol = lane & 15;
  int m0 = blockIdx.y * 128, n0 = blockIdx.x * 128;
  v4f acc[4][4] = {};
  // staging: wave w covers rows [w*32, w*32+32) in 2 issues of 16 rows;
  // lane -> row w*32 + issue*16 + (lane>>2), 16B chunk (lane&3)
  int sr = lane >> 2, sc = lane & 3;
  const u16* gA = X  + (size_t)(m0 + w * 32 + sr) * K + sc * 8;
  const u16* gB = Wt + (size_t)(n0 + w * 32 + sr) * K + sc * 8;
  u16* lA = As + (w * 32) * 32;
  u16* lB = Bs + (w * 32) * 32;
  for (int k0 = 0; k0 < K; k0 += 32) {
    __syncthreads();
    glds16(gA + k0, lA);
    glds16(gA + k0 + (size_t)16 * K, lA + 16 * 32);
    glds16(gB + k0, lB);
    glds16(gB + k0 + (size_t)16 * K, lB + 16 * 32);
    __syncthreads();
    v8s a[4], b[4];
#pragma unroll
    for (int i = 0; i < 4; ++i) {
      a[i] = *(v8s*)&As[(wm * 64 + i * 16 + lcol) * 32 + quad * 8];
      b[i] = *(v8s*)&Bs[(wn * 64 + i * 16 + lcol) * 32 + quad * 8];
    }
#pragma unroll
    for (int i = 0; i < 4; ++i)
#pragma unroll
      for (int j = 0; j < 4; ++j)
        acc[i][j] = mfma16(a[i], b[j], acc[i][j]);
  }
#pragma unroll
  for (int i = 0; i < 4; ++i) {
    int mb = m0 + wm * 64 + i * 16 + quad * 4;
#pragma unroll
    for (int j = 0; j < 4; ++j) {
      int n = n0 + wn * 64 + j * 16 + lcol;
#pragma unroll
      for (int r = 0; r < 4; ++r) {
        float v = acc[i][j][r];
        if (bias) v += bias[n];
        if (resf) v += resf[(size_t)(mb + r) * N + n];
        if (relu) v = fmaxf(v, 0.f);
        if (Yb) Yb[(size_t)(mb + r) * N + n] = f2b(v);
        else    Yf[(size_t)(mb + r) * N + n] = v;
      }
    }
  }
}

// ------- Flash attention (causal); QKV packed [M,3072], 64-query tile ----
__global__ __launch_bounds__(256) void attn_kernel(const u16* __restrict__ QKV,
    u16* __restrict__ Ob) {
  int bh = blockIdx.x;  // b*NH + h
  int qt = blockIdx.y;
  int b = bh >> 4, h = bh & 15;
  int tid = threadIdx.x, lane = tid & 63, wid = tid >> 6;
  int quad = lane >> 4, lcol = lane & 15;
  __shared__ __align__(16) u16 Qs[64 * 72];
  __shared__ __align__(16) u16 Ks[64 * 72];
  __shared__ __align__(16) u16 Vts[64 * 72];
  __shared__ __align__(16) u16 Ps[4][16 * 72];
  int r = tid >> 2, g = tid & 3;
  size_t qrow = ((size_t)(b * T_ + qt * 64 + r)) * QKVC + h * HD_;
  *(uint4*)&Qs[r * 72 + g * 8]      = *(const uint4*)&QKV[qrow + g * 8];
  *(uint4*)&Qs[r * 72 + 32 + g * 8] = *(const uint4*)&QKV[qrow + 32 + g * 8];
  __syncthreads();
  v8s aq0 = *(v8s*)&Qs[(wid * 16 + lcol) * 72 + quad * 8];
  v8s aq1 = *(v8s*)&Qs[(wid * 16 + lcol) * 72 + 32 + quad * 8];
  float m_i[4], l_i[4];
  v4f accO[4];
  v4f zero = {0.f, 0.f, 0.f, 0.f};
#pragma unroll
  for (int i = 0; i < 4; ++i) { m_i[i] = -__builtin_inff(); l_i[i] = 0.f; accO[i] = zero; }
  int nkb = qt + 1;
  for (int kb = 0; kb < nkb; ++kb) {
    __syncthreads();
    size_t krow = ((size_t)(b * T_ + kb * 64 + r)) * QKVC + h * HD_ + 1024;
    *(uint4*)&Ks[r * 72 + g * 8]      = *(const uint4*)&QKV[krow + g * 8];
    *(uint4*)&Ks[r * 72 + 32 + g * 8] = *(const uint4*)&QKV[krow + 32 + g * 8];
    union { uint4 v; u16 s[8]; } vv;
    vv.v = *(const uint4*)&QKV[krow + 1024 + g * 8];
#pragma unroll
    for (int e = 0; e < 8; ++e) Vts[(g * 8 + e) * 72 + r] = vv.s[e];
    vv.v = *(const uint4*)&QKV[krow + 1024 + 32 + g * 8];
#pragma unroll
    for (int e = 0; e < 8; ++e) Vts[(32 + g * 8 + e) * 72 + r] = vv.s[e];
    __syncthreads();
    // scores: 16 q-rows x 64 keys per wave
    float sc[4][4], p[4][4], mx[4];
#pragma unroll
    for (int reg = 0; reg < 4; ++reg) mx[reg] = -__builtin_inff();
#pragma unroll
    for (int cg = 0; cg < 4; ++cg) {
      v4f acc = zero;
      v8s bk0 = *(v8s*)&Ks[(cg * 16 + lcol) * 72 + quad * 8];
      v8s bk1 = *(v8s*)&Ks[(cg * 16 + lcol) * 72 + 32 + quad * 8];
      acc = mfma16(aq0, bk0, acc);
      acc = mfma16(aq1, bk1, acc);
      int tk = kb * 64 + cg * 16 + lcol;
#pragma unroll
      for (int reg = 0; reg < 4; ++reg) {
        int tq = qt * 64 + wid * 16 + quad * 4 + reg;
        float s = (tk <= tq) ? acc[reg] * 0.125f : -__builtin_inff();
        sc[cg][reg] = s;
        mx[reg] = fmaxf(mx[reg], s);
      }
    }
#pragma unroll
    for (int reg = 0; reg < 4; ++reg) {
      float v = mx[reg];
      v = fmaxf(v, __shfl_xor(v, 1));
      v = fmaxf(v, __shfl_xor(v, 2));
      v = fmaxf(v, __shfl_xor(v, 4));
      v = fmaxf(v, __shfl_xor(v, 8));
      float mnew = fmaxf(m_i[reg], v);
      float alpha = exp2f((m_i[reg] - mnew) * 1.44269504f);
      float ps = 0.f;
#pragma unroll
      for (int cg = 0; cg < 4; ++cg) {
        float pv = exp2f((sc[cg][reg] - mnew) * 1.44269504f);
        p[cg][reg] = pv;
        ps += pv;
      }
      ps += __shfl_xor(ps, 1);
      ps += __shfl_xor(ps, 2);
      ps += __shfl_xor(ps, 4);
      ps += __shfl_xor(ps, 8);
      l_i[reg] = l_i[reg] * alpha + ps;
      m_i[reg] = mnew;
#pragma unroll
      for (int df = 0; df < 4; ++df) accO[df][reg] *= alpha;
    }
    // P: C-layout -> LDS -> A-layout
#pragma unroll
    for (int cg = 0; cg < 4; ++cg)
#pragma unroll
      for (int reg = 0; reg < 4; ++reg)
        Ps[wid][(quad * 4 + reg) * 72 + cg * 16 + lcol] = f2b(p[cg][reg]);
    __syncthreads();
#pragma unroll
    for (int ks = 0; ks < 2; ++ks) {
      v8s ap = *(v8s*)&Ps[wid][lcol * 72 + ks * 32 + quad * 8];
#pragma unroll
      for (int df = 0; df < 4; ++df) {
        v8s bv = *(v8s*)&Vts[(df * 16 + lcol) * 72 + ks * 32 + quad * 8];
        accO[df] = mfma16(ap, bv, accO[df]);
      }
    }
  }
#pragma unroll
  for (int df = 0; df < 4; ++df)
#pragma unroll
    for (int reg = 0; reg < 4; ++reg) {
      int q = qt * 64 + wid * 16 + quad * 4 + reg;
      float o = accO[df][reg] / l_i[reg];
      Ob[((size_t)(b * T_ + q)) * C_ + h * HD_ + df * 16 + lcol] = f2b(o);
    }
}

extern "C" void kernel_launch(void* const* d_in, const int* in_sizes, int n_in,
                              void* d_out, int out_size, void* d_ws, size_t ws_size,
                              hipStream_t stream) {
  (void)in_sizes; (void)n_in; (void)out_size; (void)ws_size;
  const float* x    = (const float*)d_in[0];
  const float* ln1w = (const float*)d_in[1];
  const float* ln1b = (const float*)d_in[2];
  const float* Wq   = (const float*)d_in[3];
  const float* Wk   = (const float*)d_in[4];
  const float* Wv   = (const float*)d_in[5];
  const float* Wp   = (const float*)d_in[6];
  const float* bp   = (const float*)d_in[7];
  const float* ln2w = (const float*)d_in[8];
  const float* ln2b = (const float*)d_in[9];
  const float* W1   = (const float*)d_in[10];
  const float* b1   = (const float*)d_in[11];
  const float* W2   = (const float*)d_in[12];
  const float* b2   = (const float*)d_in[13];
  float* out = (float*)d_out;
  char* ws = (char*)d_ws;
  const size_t MB = 1024 * 1024;
  u16*   h1    = (u16*)(ws);             // 0..8 MB (h2 overlays later)
  u16*   QKVb  = (u16*)(ws + 8  * MB);   // 8..32 MB [4096,3072] bf16
  u16*   Ob    = (u16*)(ws + 32 * MB);   // 32..40 MB
  float* xa    = (float*)(ws + 40 * MB); // 40..56 MB fp32
  u16*   h2    = (u16*)(ws);             // overlays h1 (dead)
  u16*   f1    = (u16*)(ws + 8 * MB);    // 8..40 MB, overlays QKVb+Ob (dead)
  u16*   Wqkvt = (u16*)(ws + 56 * MB);   // 56..62 MB [3072,1024] bf16
  u16*   Wpt   = (u16*)(ws + 62 * MB);   // 62..64 MB [1024,1024]
  u16*   W1t   = (u16*)(ws + 64 * MB);   // 64..72 MB [4096,1024]
  u16*   W2t   = (u16*)(ws + 72 * MB);   // 72..80 MB [1024,4096]

  // weight convert+transpose (runs every call; ~15 us)
  wcvt_kernel<<<dim3(32, 32),  256, 0, stream>>>(Wq, Wqkvt,                1024, 1024);
  wcvt_kernel<<<dim3(32, 32),  256, 0, stream>>>(Wk, Wqkvt + 1024 * 1024,  1024, 1024);
  wcvt_kernel<<<dim3(32, 32),  256, 0, stream>>>(Wv, Wqkvt + 2048 * 1024,  1024, 1024);
  wcvt_kernel<<<dim3(32, 32),  256, 0, stream>>>(Wp, Wpt,                  1024, 1024);
  wcvt_kernel<<<dim3(128, 32), 256, 0, stream>>>(W1, W1t,                  1024, 4096);
  wcvt_kernel<<<dim3(32, 128), 256, 0, stream>>>(W2, W2t,                  4096, 1024);

  ln_kernel<<<NT, 256, 0, stream>>>(x, ln1w, ln1b, h1);
  gemm_bt<<<dim3(QKVC / 128, NT / 128), 256, 0, stream>>>(h1, Wqkvt, nullptr, nullptr, QKVb, nullptr, NT, QKVC, C_, 0);
  attn_kernel<<<dim3(B_ * NH_, T_ / 64), 256, 0, stream>>>(QKVb, Ob);
  gemm_bt<<<dim3(C_ / 128, NT / 128), 256, 0, stream>>>(Ob, Wpt, bp, x, nullptr, xa, NT, C_, C_, 0);
  ln_kernel<<<NT, 256, 0, stream>>>(xa, ln2w, ln2b, h2);
  gemm_bt<<<dim3(FF_ / 128, NT / 128), 256, 0, stream>>>(h2, W1t, b1, nullptr, f1, nullptr, NT, FF_, C_, 1);
  gemm_bt<<<dim3(C_ / 128, NT / 128), 256, 0, stream>>>(f1, W2t, b2, xa, nullptr, out, NT, C_, FF_, 0);
}

// Round 5
// 461.642 us; speedup vs baseline: 1.6874x; 1.1778x over previous
//
#include <hip/hip_runtime.h>
#include <hip/hip_bf16.h>

using u16 = unsigned short;
typedef short v8s __attribute__((ext_vector_type(8)));
typedef float v4f __attribute__((ext_vector_type(4)));

#define B_ 2
#define T_ 2048
#define C_ 1024
#define NH_ 16
#define HD_ 64
#define FF_ 4096
#define NT (B_*T_)
#define QKVC 3072

__device__ __forceinline__ u16 f2b(float f) {
  union { float f; unsigned int i; } v; v.f = f;
  unsigned int r = (v.i + 0x7FFFu + ((v.i >> 16) & 1u)) >> 16;
  return (u16)r;
}
__device__ __forceinline__ v4f mfma16(v8s a, v8s b, v4f c) {
  return __builtin_amdgcn_mfma_f32_16x16x32_bf16(a, b, c, 0, 0, 0);
}
__device__ __forceinline__ void glds16(const u16* g, u16* l) {
  __builtin_amdgcn_global_load_lds(
      (const __attribute__((address_space(1))) unsigned int*)g,
      (__attribute__((address_space(3))) unsigned int*)l, 16, 0, 0);
}

// ------- weight convert+transpose: W[K,N] fp32 -> Wt[N,K] bf16 -------
__global__ __launch_bounds__(256) void wcvt_kernel(const float* __restrict__ W,
    u16* __restrict__ Wt, int K, int N) {
  __shared__ float t[32][33];
  int tx = threadIdx.x & 31, ty = threadIdx.x >> 5;
  int n0 = blockIdx.x * 32, k0 = blockIdx.y * 32;
#pragma unroll
  for (int j = 0; j < 4; ++j)
    t[ty + j * 8][tx] = W[(size_t)(k0 + ty + j * 8) * N + n0 + tx];
  __syncthreads();
#pragma unroll
  for (int j = 0; j < 4; ++j)
    Wt[(size_t)(n0 + ty + j * 8) * K + k0 + tx] = f2b(t[tx][ty + j * 8]);
}

// ------- LayerNorm: fp32 in -> bf16 out, one block per row (C=1024) -------
__global__ __launch_bounds__(256) void ln_kernel(const float* __restrict__ x,
    const float* __restrict__ w, const float* __restrict__ b, u16* __restrict__ y) {
  int row = blockIdx.x;
  int tid = threadIdx.x;
  const float* xr = x + (size_t)row * C_;
  float4 f4 = *(const float4*)&xr[tid * 4];
  float f[4] = {f4.x, f4.y, f4.z, f4.w};
  float s1 = 0.f, s2 = 0.f;
#pragma unroll
  for (int i = 0; i < 4; ++i) { s1 += f[i]; s2 += f[i] * f[i]; }
#pragma unroll
  for (int off = 32; off > 0; off >>= 1) {
    s1 += __shfl_down(s1, off);
    s2 += __shfl_down(s2, off);
  }
  __shared__ float red[10];
  int lane = tid & 63, wid = tid >> 6;
  if (lane == 0) { red[wid] = s1; red[4 + wid] = s2; }
  __syncthreads();
  if (tid == 0) {
    float a = red[0] + red[1] + red[2] + red[3];
    float q = red[4] + red[5] + red[6] + red[7];
    float mu = a * (1.f / C_);
    float var = q * (1.f / C_) - mu * mu;
    red[8] = mu; red[9] = rsqrtf(var + 1e-5f);
  }
  __syncthreads();
  float mu = red[8], rs = red[9];
  union { uint2 v; u16 s[4]; } st;
#pragma unroll
  for (int i = 0; i < 4; ++i) {
    int c = tid * 4 + i;
    st.s[i] = f2b((f[i] - mu) * rs * w[c] + b[c]);
  }
  *(uint2*)&y[(size_t)row * C_ + tid * 4] = st.v;
}

// ------- GEMM (m97): Y[M,N] = X[M,K] @ Wt[N,K]^T, 128x128x32 tile --------
__global__ __launch_bounds__(256) void gemm_bt(const u16* __restrict__ X,
    const u16* __restrict__ Wt, const float* __restrict__ bias,
    const float* __restrict__ resf, u16* __restrict__ Yb, float* __restrict__ Yf,
    int M, int N, int K, int relu) {
  __shared__ __align__(16) u16 As[128 * 32];
  __shared__ __align__(16) u16 Bs[128 * 32];
  int tid = threadIdx.x, lane = tid & 63, w = tid >> 6;
  int wm = w >> 1, wn = w & 1, quad = lane >> 4, lcol = lane & 15;
  int m0 = blockIdx.y * 128, n0 = blockIdx.x * 128;
  v4f acc[4][4] = {};
  int sr = lane >> 2, sc = lane & 3;
  const u16* gA = X  + (size_t)(m0 + w * 32 + sr) * K + sc * 8;
  const u16* gB = Wt + (size_t)(n0 + w * 32 + sr) * K + sc * 8;
  u16* lA = As + (w * 32) * 32;
  u16* lB = Bs + (w * 32) * 32;
  for (int k0 = 0; k0 < K; k0 += 32) {
    __syncthreads();
    glds16(gA + k0, lA);
    glds16(gA + k0 + (size_t)16 * K, lA + 16 * 32);
    glds16(gB + k0, lB);
    glds16(gB + k0 + (size_t)16 * K, lB + 16 * 32);
    __syncthreads();
    v8s a[4], b[4];
#pragma unroll
    for (int i = 0; i < 4; ++i) {
      a[i] = *(v8s*)&As[(wm * 64 + i * 16 + lcol) * 32 + quad * 8];
      b[i] = *(v8s*)&Bs[(wn * 64 + i * 16 + lcol) * 32 + quad * 8];
    }
#pragma unroll
    for (int i = 0; i < 4; ++i)
#pragma unroll
      for (int j = 0; j < 4; ++j)
        acc[i][j] = mfma16(a[i], b[j], acc[i][j]);
  }
#pragma unroll
  for (int i = 0; i < 4; ++i) {
    int mb = m0 + wm * 64 + i * 16 + quad * 4;
#pragma unroll
    for (int j = 0; j < 4; ++j) {
      int n = n0 + wn * 64 + j * 16 + lcol;
#pragma unroll
      for (int r = 0; r < 4; ++r) {
        float v = acc[i][j][r];
        if (bias) v += bias[n];
        if (resf) v += resf[(size_t)(mb + r) * N + n];
        if (relu) v = fmaxf(v, 0.f);
        if (Yb) Yb[(size_t)(mb + r) * N + n] = f2b(v);
        else    Yf[(size_t)(mb + r) * N + n] = v;
      }
    }
  }
}

// ------- GEMM variant for small N: 128x64x32 tile (2 blocks/CU at N=1024) --
__global__ __launch_bounds__(256) void gemm_bt_n64(const u16* __restrict__ X,
    const u16* __restrict__ Wt, const float* __restrict__ bias,
    const float* __restrict__ resf, u16* __restrict__ Yb, float* __restrict__ Yf,
    int M, int N, int K, int relu) {
  __shared__ __align__(16) u16 As[128 * 32];
  __shared__ __align__(16) u16 Bs[64 * 32];
  int tid = threadIdx.x, lane = tid & 63, w = tid >> 6;
  int wm = w >> 1, wn = w & 1, quad = lane >> 4, lcol = lane & 15;
  int m0 = blockIdx.y * 128, n0 = blockIdx.x * 64;
  v4f acc[4][2] = {};
  int sr = lane >> 2, sc = lane & 3;
  const u16* gA = X  + (size_t)(m0 + w * 32 + sr) * K + sc * 8;
  const u16* gB = Wt + (size_t)(n0 + w * 16 + sr) * K + sc * 8;
  u16* lA = As + (w * 32) * 32;
  u16* lB = Bs + (w * 16) * 32;
  for (int k0 = 0; k0 < K; k0 += 32) {
    __syncthreads();
    glds16(gA + k0, lA);
    glds16(gA + k0 + (size_t)16 * K, lA + 16 * 32);
    glds16(gB + k0, lB);
    __syncthreads();
    v8s a[4], b[2];
#pragma unroll
    for (int i = 0; i < 4; ++i)
      a[i] = *(v8s*)&As[(wm * 64 + i * 16 + lcol) * 32 + quad * 8];
#pragma unroll
    for (int j = 0; j < 2; ++j)
      b[j] = *(v8s*)&Bs[(wn * 32 + j * 16 + lcol) * 32 + quad * 8];
#pragma unroll
    for (int i = 0; i < 4; ++i)
#pragma unroll
      for (int j = 0; j < 2; ++j)
        acc[i][j] = mfma16(a[i], b[j], acc[i][j]);
  }
#pragma unroll
  for (int i = 0; i < 4; ++i) {
    int mb = m0 + wm * 64 + i * 16 + quad * 4;
#pragma unroll
    for (int j = 0; j < 2; ++j) {
      int n = n0 + wn * 32 + j * 16 + lcol;
#pragma unroll
      for (int r = 0; r < 4; ++r) {
        float v = acc[i][j][r];
        if (bias) v += bias[n];
        if (resf) v += resf[(size_t)(mb + r) * N + n];
        if (relu) v = fmaxf(v, 0.f);
        if (Yb) Yb[(size_t)(mb + r) * N + n] = f2b(v);
        else    Yf[(size_t)(mb + r) * N + n] = v;
      }
    }
  }
}

// ------- V transpose: QKV v-columns -> VT[bh][d][t] bf16 ------------------
__global__ __launch_bounds__(256) void vt_kernel(const u16* __restrict__ QKV,
    u16* __restrict__ VT) {
  int bh = blockIdx.x, tt = blockIdx.y;
  int b = bh >> 4, h = bh & 15;
  int tid = threadIdx.x;
  __shared__ u16 L[64 * 72];  // L[d][t]
  int r = tid >> 2, g = tid & 3;
  size_t row = ((size_t)(b * T_ + tt * 64 + r)) * QKVC + 2 * C_ + h * HD_;
  union { uint4 v; u16 s[8]; } a0, a1;
  a0.v = *(const uint4*)&QKV[row + g * 8];
  a1.v = *(const uint4*)&QKV[row + 32 + g * 8];
#pragma unroll
  for (int e = 0; e < 8; ++e) L[(g * 8 + e) * 72 + r] = a0.s[e];
#pragma unroll
  for (int e = 0; e < 8; ++e) L[(32 + g * 8 + e) * 72 + r] = a1.s[e];
  __syncthreads();
  size_t orow = ((size_t)(bh * 64 + r)) * T_ + tt * 64;
  *(uint4*)&VT[orow + g * 8]      = *(uint4*)&L[r * 72 + g * 8];
  *(uint4*)&VT[orow + 32 + g * 8] = *(uint4*)&L[r * 72 + 32 + g * 8];
}

// ------- Flash attention (causal), S^T-form, 64-query tile per block ------
__global__ __launch_bounds__(256) void attn_kernel(const u16* __restrict__ QKV,
    const u16* __restrict__ VT, u16* __restrict__ Ob) {
  int bh = blockIdx.x, qt = blockIdx.y;
  int b = bh >> 4, h = bh & 15;
  int tid = threadIdx.x, lane = tid & 63, wid = tid >> 6;
  int quad = lane >> 4, lcol = lane & 15;
  __shared__ __align__(16) u16 Qs[64 * 72];
  __shared__ __align__(16) u16 Ks[64 * 72];
  __shared__ __align__(16) u16 Vs[64 * 72];   // V^T tile: [d][t]
  __shared__ __align__(16) u16 Ps[4][16 * 72]; // per-wave P[q][kt]
  int r = tid >> 2, g = tid & 3;
  size_t qrow = ((size_t)(b * T_ + qt * 64 + r)) * QKVC + h * HD_;
  *(uint4*)&Qs[r * 72 + g * 8]      = *(const uint4*)&QKV[qrow + g * 8];
  *(uint4*)&Qs[r * 72 + 32 + g * 8] = *(const uint4*)&QKV[qrow + 32 + g * 8];
  __syncthreads();
  v8s bq0 = *(v8s*)&Qs[(wid * 16 + lcol) * 72 + quad * 8];
  v8s bq1 = *(v8s*)&Qs[(wid * 16 + lcol) * 72 + 32 + quad * 8];
  float m_i = -__builtin_inff(), l_i = 0.f;
  v4f accO[4] = {};
  int q_glob = qt * 64 + wid * 16 + lcol;
  const float SC = 0.125f * 1.44269504f;  // hd^-0.5 * log2(e), applied in exp arg
  for (int kb = 0; kb <= qt; ++kb) {
    __syncthreads();
    size_t krow = ((size_t)(b * T_ + kb * 64 + r)) * QKVC + C_ + h * HD_;
    *(uint4*)&Ks[r * 72 + g * 8]      = *(const uint4*)&QKV[krow + g * 8];
    *(uint4*)&Ks[r * 72 + 32 + g * 8] = *(const uint4*)&QKV[krow + 32 + g * 8];
    size_t vrow = ((size_t)(bh * 64 + r)) * T_ + kb * 64;
    *(uint4*)&Vs[r * 72 + g * 8]      = *(const uint4*)&VT[vrow + g * 8];
    *(uint4*)&Vs[r * 72 + 32 + g * 8] = *(const uint4*)&VT[vrow + 32 + g * 8];
    __syncthreads();
    // S^T: C[kt][q] = sum_d K[kt][d] * Q[q][d]
    v4f s[4];
#pragma unroll
    for (int cg = 0; cg < 4; ++cg) {
      v4f acc = {};
      v8s ak0 = *(v8s*)&Ks[(cg * 16 + lcol) * 72 + quad * 8];
      v8s ak1 = *(v8s*)&Ks[(cg * 16 + lcol) * 72 + 32 + quad * 8];
      acc = mfma16(ak0, bq0, acc);
      acc = mfma16(ak1, bq1, acc);
      s[cg] = acc;
    }
    float mx = -__builtin_inff();
#pragma unroll
    for (int cg = 0; cg < 4; ++cg)
#pragma unroll
      for (int rg = 0; rg < 4; ++rg) {
        int kt = kb * 64 + cg * 16 + quad * 4 + rg;
        float v = (kt <= q_glob) ? s[cg][rg] : -__builtin_inff();
        s[cg][rg] = v;
        mx = fmaxf(mx, v);
      }
    mx = fmaxf(mx, __shfl_xor(mx, 16));
    mx = fmaxf(mx, __shfl_xor(mx, 32));
    float mnew = fmaxf(m_i, mx);
    float alpha = exp2f((m_i - mnew) * SC);
    float base = mnew * SC;
    float ps = 0.f;
#pragma unroll
    for (int cg = 0; cg < 4; ++cg) {
      union { u16 s4[4]; unsigned long long ll; } pk;
#pragma unroll
      for (int rg = 0; rg < 4; ++rg) {
        float pv = exp2f(s[cg][rg] * SC - base);
        ps += pv;
        pk.s4[rg] = f2b(pv);
      }
      *(unsigned long long*)&Ps[wid][lcol * 72 + cg * 16 + quad * 4] = pk.ll;
    }
    ps += __shfl_xor(ps, 16);
    ps += __shfl_xor(ps, 32);
    l_i = l_i * alpha + ps;
    m_i = mnew;
#pragma unroll
    for (int df = 0; df < 4; ++df)
#pragma unroll
      for (int rg = 0; rg < 4; ++rg) accO[df][rg] *= alpha;
    // PV: O^T[d][q] += V^T[d][kt] * P[q][kt]  (wave-private Ps, no barrier)
    v8s bp0 = *(v8s*)&Ps[wid][lcol * 72 + quad * 8];
    v8s bp1 = *(v8s*)&Ps[wid][lcol * 72 + 32 + quad * 8];
#pragma unroll
    for (int df = 0; df < 4; ++df) {
      v8s av0 = *(v8s*)&Vs[(df * 16 + lcol) * 72 + quad * 8];
      v8s av1 = *(v8s*)&Vs[(df * 16 + lcol) * 72 + 32 + quad * 8];
      accO[df] = mfma16(av0, bp0, accO[df]);
      accO[df] = mfma16(av1, bp1, accO[df]);
    }
  }
  float inv = 1.f / l_i;
  size_t orow = ((size_t)(b * T_ + qt * 64 + wid * 16 + lcol)) * C_ + h * HD_;
#pragma unroll
  for (int df = 0; df < 4; ++df) {
    union { u16 s4[4]; unsigned long long ll; } ok;
#pragma unroll
    for (int rg = 0; rg < 4; ++rg) ok.s4[rg] = f2b(accO[df][rg] * inv);
    *(unsigned long long*)&Ob[orow + df * 16 + quad * 4] = ok.ll;
  }
}

extern "C" void kernel_launch(void* const* d_in, const int* in_sizes, int n_in,
                              void* d_out, int out_size, void* d_ws, size_t ws_size,
                              hipStream_t stream) {
  (void)in_sizes; (void)n_in; (void)out_size; (void)ws_size;
  const float* x    = (const float*)d_in[0];
  const float* ln1w = (const float*)d_in[1];
  const float* ln1b = (const float*)d_in[2];
  const float* Wq   = (const float*)d_in[3];
  const float* Wk   = (const float*)d_in[4];
  const float* Wv   = (const float*)d_in[5];
  const float* Wp   = (const float*)d_in[6];
  const float* bp   = (const float*)d_in[7];
  const float* ln2w = (const float*)d_in[8];
  const float* ln2b = (const float*)d_in[9];
  const float* W1   = (const float*)d_in[10];
  const float* b1   = (const float*)d_in[11];
  const float* W2   = (const float*)d_in[12];
  const float* b2   = (const float*)d_in[13];
  float* out = (float*)d_out;
  char* ws = (char*)d_ws;
  const size_t MB = 1024 * 1024;
  u16*   h1    = (u16*)(ws);             // 0..8 MB
  u16*   VT    = (u16*)(ws);             // 0..8 MB, overlays h1 (dead after QKV gemm)
  u16*   QKVb  = (u16*)(ws + 8  * MB);   // 8..32 MB [4096,3072] bf16
  u16*   Ob    = (u16*)(ws + 32 * MB);   // 32..40 MB
  float* xa    = (float*)(ws + 40 * MB); // 40..56 MB fp32
  u16*   h2    = (u16*)(ws);             // overlays VT (dead after attn)
  u16*   f1    = (u16*)(ws + 8 * MB);    // 8..40 MB, overlays QKVb+Ob (dead)
  u16*   Wqkvt = (u16*)(ws + 56 * MB);   // 56..62 MB [3072,1024] bf16
  u16*   Wpt   = (u16*)(ws + 62 * MB);   // 62..64 MB [1024,1024]
  u16*   W1t   = (u16*)(ws + 64 * MB);   // 64..72 MB [4096,1024]
  u16*   W2t   = (u16*)(ws + 72 * MB);   // 72..80 MB [1024,4096]

  wcvt_kernel<<<dim3(32, 32),  256, 0, stream>>>(Wq, Wqkvt,                1024, 1024);
  wcvt_kernel<<<dim3(32, 32),  256, 0, stream>>>(Wk, Wqkvt + 1024 * 1024,  1024, 1024);
  wcvt_kernel<<<dim3(32, 32),  256, 0, stream>>>(Wv, Wqkvt + 2048 * 1024,  1024, 1024);
  wcvt_kernel<<<dim3(32, 32),  256, 0, stream>>>(Wp, Wpt,                  1024, 1024);
  wcvt_kernel<<<dim3(128, 32), 256, 0, stream>>>(W1, W1t,                  1024, 4096);
  wcvt_kernel<<<dim3(32, 128), 256, 0, stream>>>(W2, W2t,                  4096, 1024);

  ln_kernel<<<NT, 256, 0, stream>>>(x, ln1w, ln1b, h1);
  gemm_bt<<<dim3(QKVC / 128, NT / 128), 256, 0, stream>>>(h1, Wqkvt, nullptr, nullptr, QKVb, nullptr, NT, QKVC, C_, 0);
  vt_kernel<<<dim3(B_ * NH_, T_ / 64), 256, 0, stream>>>(QKVb, VT);
  attn_kernel<<<dim3(B_ * NH_, T_ / 64), 256, 0, stream>>>(QKVb, VT, Ob);
  gemm_bt_n64<<<dim3(C_ / 64, NT / 128), 256, 0, stream>>>(Ob, Wpt, bp, x, nullptr, xa, NT, C_, C_, 0);
  ln_kernel<<<NT, 256, 0, stream>>>(xa, ln2w, ln2b, h2);
  gemm_bt<<<dim3(FF_ / 128, NT / 128), 256, 0, stream>>>(h2, W1t, b1, nullptr, f1, nullptr, NT, FF_, C_, 1);
  gemm_bt_n64<<<dim3(C_ / 64, NT / 128), 256, 0, stream>>>(f1, W2t, b2, xa, nullptr, out, NT, C_, FF_, 0);
}